// Round 23
// baseline (836.728 us; speedup 1.0000x reference)
//
#include <hip/hip_runtime.h>

#define LNUM 4
#define DMODEL 1024
#define NHEAD 16
#define FDIM 4096
#define BATCH 4
#define SEQ 1024
#define HDIM 64
#define KBAND 8
#define MROWS (BATCH * SEQ)

typedef __attribute__((ext_vector_type(8))) __bf16 bf16x8;
typedef __attribute__((ext_vector_type(4))) float f32x4;
typedef __attribute__((ext_vector_type(8))) unsigned short u16x8;

__device__ __forceinline__ unsigned short f2bf(float f) {
  unsigned int u = __builtin_bit_cast(unsigned int, f);
  u = u + 0x7fffu + ((u >> 16) & 1u);
  return (unsigned short)(u >> 16);
}
__device__ __forceinline__ float bf2f(unsigned short h) {
  unsigned int u = ((unsigned int)h) << 16;
  return __builtin_bit_cast(float, u);
}

#define GLOAD16(gp, lp)                                                        \
  __builtin_amdgcn_global_load_lds(                                            \
      (const __attribute__((address_space(1))) void*)(gp),                     \
      (__attribute__((address_space(3))) void*)(lp), 16, 0, 0)

// ---------------- fused fp32 -> bf16 conversion (all 5 regions, 1 launch) ---
// R23 = R22 with the compile fix: nontemporal builtins need clang ext_vector
// types (f32x4), not HIP_vector_type (float4). Direct-indexed (max
// concurrency), 8 elems/thread, 26624 blocks, NT loads+stores (don't
// pollute L2/L3 ahead of GEMMs). History: R20 4/thr 53k blk = 78us
// (2.8TB/s); R21 8/thr 2048 blk stride = 87us (2.5TB/s) -> memory-
// PARALLELISM-bound; restore high block count + 8/thr ILP.
#define CVT_O1 12582912L
#define CVT_O2 16777216L
#define CVT_O3 33554432L
#define CVT_O4 50331648L
#define CVT_TOT 54525952L
__global__ __launch_bounds__(256) void cvt_all(const float* __restrict__ s0,
                                               const float* __restrict__ s1,
                                               const float* __restrict__ s2,
                                               const float* __restrict__ s3,
                                               const float* __restrict__ s4,
                                               unsigned short* __restrict__ dst) {
  const long i = ((long)blockIdx.x * 256 + threadIdx.x) * 8;
  if (i >= CVT_TOT) return;
  const float* sp;
  if (i < CVT_O1)      sp = s0 + i;
  else if (i < CVT_O2) sp = s1 + (i - CVT_O1);
  else if (i < CVT_O3) sp = s2 + (i - CVT_O2);
  else if (i < CVT_O4) sp = s3 + (i - CVT_O3);
  else                 sp = s4 + (i - CVT_O4);
  f32x4 v0 = __builtin_nontemporal_load(reinterpret_cast<const f32x4*>(sp));
  f32x4 v1 = __builtin_nontemporal_load(reinterpret_cast<const f32x4*>(sp + 4));
  u16x8 o;
  o[0] = f2bf(v0[0]); o[1] = f2bf(v0[1]); o[2] = f2bf(v0[2]); o[3] = f2bf(v0[3]);
  o[4] = f2bf(v1[0]); o[5] = f2bf(v1[1]); o[6] = f2bf(v1[2]); o[7] = f2bf(v1[3]);
  __builtin_nontemporal_store(o, reinterpret_cast<u16x8*>(dst + i));
}

// ---------------- 128x128 bf16 GEMM, BK=64 single-buffer (R16 exact) --------
// CHAMPION config (R16/R19/R20/R21: GEMMs ~50us, FETCH 25MB, MfmaUtil 27%,
// conflicts 131K). Measured-closed axes: schedule (6 variants all regress vs
// drain-0+TLP at these shapes); tile (256^2, 256x128 lose); BK (32 worse).
// Per iter: stage 8 gload_lds (32KB) -> __syncthreads -> 16 ds_read +
// 32 MFMA -> __syncthreads; latency hidden by 3-4 resident blocks/CU (m114).
// Swizzle for 128B rows: stored (row,g) holds source granule g^((row>>1)&7);
// read quad = kg^((fr>>1)&7) -> conflict-free. 8x8 super-tile under XCD
// chunking: per-XCD working set = L2 (FETCH 53->25MB). Epilogue: wave-
// private LDS transpose, full 64B-line stores.
// blockIdx.z = K-split; EPI: 0 bf16+bias, 1 bf16+bias+gelu, 2 bf16 partial.
template <int EPI>
__global__ __launch_bounds__(256, 4) void gemm128(const unsigned short* __restrict__ A,
                                                  const unsigned short* __restrict__ W,
                                                  const float* __restrict__ bias,
                                                  unsigned short* __restrict__ Cout,
                                                  int Ndim, int Kdim, int Ks) {
  __shared__ unsigned short SH[16384];  // As=SH[0:8192], Bs=SH[8192:16384]
  unsigned short* As = SH;
  unsigned short* Bs = SH + 8192;
  const int tid = threadIdx.x;
  const int wave = tid >> 6;
  const int lane = tid & 63;

  const int gx = gridDim.x, gy = gridDim.y;
  const int nwg = gx * gy;
  const int lin = blockIdx.x + blockIdx.y * gx;
  const int q8 = nwg >> 3, r8 = nwg & 7;
  const int xcd = lin & 7, cidx = lin >> 3;
  const int cbase = (xcd < r8) ? xcd * (q8 + 1) : r8 * (q8 + 1) + (xcd - r8) * q8;
  const int swz = cbase + cidx;
  const int sup = swz >> 6, inn = swz & 63;       // super-tile = 64 wg
  const int sbm = sup % (gy >> 3);
  const int sbn = sup / (gy >> 3);
  const int bm0 = (sbm * 8 + (inn & 7)) * 128;
  const int bn0 = (sbn * 8 + (inn >> 3)) * 128;
  const int kz0 = blockIdx.z * Ks;

  const int r0 = tid >> 3;                               // 0..31
  const int c0 = (((tid & 7) ^ ((tid >> 4) & 7)) << 3);  // swizzled col elem
  const unsigned short* gA = A + (size_t)(bm0 + r0) * Kdim + kz0 + c0;
  const unsigned short* gB = W + (size_t)(bn0 + r0) * Kdim + kz0 + c0;
  const size_t rs32 = (size_t)32 * Kdim;

  f32x4 acc[4][4] = {};

  const int wr = (wave >> 1) * 64;
  const int wc = (wave & 1) * 64;
  const int fr = lane & 15;
  const int rkey = (fr >> 1) & 7;

  const int nt = Ks >> 6;
  for (int t = 0; t < nt; ++t) {
#pragma unroll
    for (int i = 0; i < 4; ++i) {
      GLOAD16(gA + i * rs32, &As[i * 2048 + wave * 512]);
      GLOAD16(gB + i * rs32, &Bs[i * 2048 + wave * 512]);
    }
    gA += 64;
    gB += 64;
    __syncthreads();
#pragma unroll
    for (int ks = 0; ks < 2; ++ks) {
      const int kg0 = (lane >> 4) + 4 * ks;
      const int kofs = ((kg0 ^ rkey) << 3);
      bf16x8 af[4], bfr[4];
#pragma unroll
      for (int i = 0; i < 4; ++i)
        af[i] = *reinterpret_cast<const bf16x8*>(&As[(wr + i * 16 + fr) * 64 + kofs]);
#pragma unroll
      for (int j = 0; j < 4; ++j)
        bfr[j] = *reinterpret_cast<const bf16x8*>(&Bs[(wc + j * 16 + fr) * 64 + kofs]);
#pragma unroll
      for (int i = 0; i < 4; ++i)
#pragma unroll
        for (int j = 0; j < 4; ++j)
          acc[i][j] = __builtin_amdgcn_mfma_f32_16x16x32_bf16(af[i], bfr[j], acc[i][j], 0, 0, 0);
    }
    __syncthreads();
  }

  const int rr = (lane >> 4) * 4;
  const int cc = lane & 15;
  const bool addb = (EPI != 2) || (blockIdx.z == 0);
  unsigned short* outZ =
      Cout + (EPI == 2 ? (size_t)blockIdx.z * ((size_t)gy * 128) * Ndim : 0);
  float bv[4];
#pragma unroll
  for (int j = 0; j < 4; ++j)
    bv[j] = addb ? bias[bn0 + wc + j * 16 + cc] : 0.0f;

  unsigned short* lt = SH + wave * 1280;
#pragma unroll
  for (int rh = 0; rh < 2; ++rh) {
#pragma unroll
    for (int cp = 0; cp < 2; ++cp) {
#pragma unroll
      for (int ii = 0; ii < 2; ++ii)
#pragma unroll
        for (int jj = 0; jj < 2; ++jj)
#pragma unroll
          for (int r = 0; r < 4; ++r) {
            float v = acc[rh * 2 + ii][cp * 2 + jj][r] + bv[cp * 2 + jj];
            if (EPI == 1) v = 0.5f * v * (1.0f + erff(v * 0.70710678118654752f));
            lt[(ii * 16 + rr + r) * 40 + jj * 16 + cc] = f2bf(v);
          }
      asm volatile("s_waitcnt lgkmcnt(0)" ::: "memory");
      const int rl = lane >> 1;
      const int chalf = (lane & 1) * 16;
      u16x8 o0 = *reinterpret_cast<const u16x8*>(&lt[rl * 40 + chalf]);
      u16x8 o1 = *reinterpret_cast<const u16x8*>(&lt[rl * 40 + chalf + 8]);
      const int m = bm0 + wr + rh * 32 + rl;
      const int n0 = bn0 + wc + cp * 32 + chalf;
      unsigned short* dst = outZ + (size_t)m * Ndim + n0;
      *reinterpret_cast<u16x8*>(dst) = o0;
      *reinterpret_cast<u16x8*>(dst + 8) = o1;
      asm volatile("s_waitcnt lgkmcnt(0)" ::: "memory");
    }
  }
}

// ---------------- banded attention: one wave per (b,h,q), lane = d ----------
__global__ __launch_bounds__(256) void attn_band(const unsigned short* __restrict__ qkv,
                                                 unsigned short* __restrict__ outp) {
  const int gw = blockIdx.x * 4 + (threadIdx.x >> 6);
  const int lane = threadIdx.x & 63;
  const int q = gw & (SEQ - 1);
  const int bh = gw >> 10;
  const int h = bh & (NHEAD - 1);
  const int b = bh >> 4;
  const size_t row0 = (size_t)(b * SEQ + q);
  const size_t stride = 3 * DMODEL;
  const float qv = bf2f(qkv[row0 * stride + h * HDIM + lane]);

  float sc[KBAND];
  float mx = -1e30f;
#pragma unroll
  for (int jj = 0; jj < KBAND; ++jj) {
    const int j = q + jj;
    const int jc = (j < SEQ) ? j : (SEQ - 1);
    float kv = bf2f(qkv[(size_t)(b * SEQ + jc) * stride + DMODEL + h * HDIM + lane]);
    float p = qv * kv;
#pragma unroll
    for (int m = 32; m; m >>= 1) p += __shfl_xor(p, m);
    p *= 0.125f;
    p = (j < SEQ) ? p : -1e30f;
    sc[jj] = p;
    mx = fmaxf(mx, p);
  }
  float denom = 0.f;
  float ov = 0.f;
#pragma unroll
  for (int jj = 0; jj < KBAND; ++jj) {
    const int j = q + jj;
    const int jc = (j < SEQ) ? j : (SEQ - 1);
    float p = __expf(sc[jj] - mx);
    p = (j < SEQ) ? p : 0.f;
    denom += p;
    ov += p * bf2f(qkv[(size_t)(b * SEQ + jc) * stride + 2 * DMODEL + h * HDIM + lane]);
  }
  ov /= denom;
  outp[row0 * DMODEL + h * HDIM + lane] = f2bf(ov);
}

// ---------------- residual(bf16, in-place) + split-K reduce + LayerNorm -----
template <int NZ>
__global__ __launch_bounds__(256) void add_ln(const float* __restrict__ srcf,
                                              unsigned short* __restrict__ xb,
                                              const unsigned short* __restrict__ part,
                                              const float* __restrict__ gw,
                                              const float* __restrict__ gb,
                                              float* __restrict__ outf) {
  const int row = blockIdx.x;
  const int tid = threadIdx.x;
  const size_t slab = (size_t)MROWS * DMODEL;
  unsigned short* xp = xb + (size_t)row * DMODEL;
  const unsigned short* pp = part + (size_t)row * DMODEL;
  float v[4];
  float s = 0.f, s2 = 0.f;
#pragma unroll
  for (int i = 0; i < 4; ++i) {
    const int idx = tid + i * 256;
    float a = srcf ? srcf[(size_t)row * DMODEL + idx] : bf2f(xp[idx]);
#pragma unroll
    for (int z = 0; z < NZ; ++z) a += bf2f(pp[z * slab + idx]);
    v[i] = a;
    s += a;
    s2 += a * a;
  }
#pragma unroll
  for (int m = 32; m; m >>= 1) {
    s += __shfl_xor(s, m);
    s2 += __shfl_xor(s2, m);
  }
  __shared__ float wsm[8];
  const int wave = tid >> 6, lane = tid & 63;
  if (lane == 0) {
    wsm[wave] = s;
    wsm[4 + wave] = s2;
  }
  __syncthreads();
  s = wsm[0] + wsm[1] + wsm[2] + wsm[3];
  s2 = wsm[4] + wsm[5] + wsm[6] + wsm[7];
  const float mean = s * (1.f / DMODEL);
  const float var = s2 * (1.f / DMODEL) - mean * mean;
  const float rstd = rsqrtf(var + 1e-5f);
#pragma unroll
  for (int i = 0; i < 4; ++i) {
    const int idx = tid + i * 256;
    const float y = (v[i] - mean) * rstd * gw[idx] + gb[idx];
    xp[idx] = f2bf(y);
    if (outf) outf[(size_t)row * DMODEL + idx] = y;
  }
}

extern "C" void kernel_launch(void* const* d_in, const int* in_sizes, int n_in,
                              void* d_out, int out_size, void* d_ws, size_t ws_size,
                              hipStream_t stream) {
  const float* src  = (const float*)d_in[0];
  const float* Wqkv = (const float*)d_in[1];
  const float* bqkv = (const float*)d_in[2];
  const float* Wo   = (const float*)d_in[3];
  const float* bo   = (const float*)d_in[4];
  const float* W1   = (const float*)d_in[5];
  const float* b1   = (const float*)d_in[6];
  const float* W2   = (const float*)d_in[7];
  const float* b2   = (const float*)d_in[8];
  const float* ln1w = (const float*)d_in[9];
  const float* ln1b = (const float*)d_in[10];
  const float* ln2w = (const float*)d_in[11];
  const float* ln2b = (const float*)d_in[12];
  float* out = (float*)d_out;

  // workspace carve-up (~168 MB of 209.7 MB). wqkv_b..xb CONTIGUOUS.
  char* p = (char*)d_ws;
  unsigned short* wqkv_b = (unsigned short*)p; p += (size_t)LNUM * 3072 * 1024 * 2;
  unsigned short* wo_b   = (unsigned short*)p; p += (size_t)LNUM * 1024 * 1024 * 2;
  unsigned short* w1_b   = (unsigned short*)p; p += (size_t)LNUM * 4096 * 1024 * 2;
  unsigned short* w2_b   = (unsigned short*)p; p += (size_t)LNUM * 1024 * 4096 * 2;
  unsigned short* xb     = (unsigned short*)p; p += (size_t)MROWS * DMODEL * 2;
  char* R = p;
  unsigned short* qkvb = (unsigned short*)R;
  unsigned short* aob  = (unsigned short*)(R + (size_t)MROWS * 3 * DMODEL * 2);
  unsigned short* hb   = (unsigned short*)R;
  unsigned short* part = (unsigned short*)(R + (size_t)MROWS * 4096 * 2);
  p = R + (size_t)MROWS * 4096 * 2 + (size_t)4 * MROWS * DMODEL * 2;
  if (ws_size < (size_t)(p - (char*)d_ws)) return;

  // single fused conversion sweep: Wqkv|Wo|W1|W2|src -> contiguous bf16
  cvt_all<<<(CVT_TOT / 8 + 255) / 256, 256, 0, stream>>>(Wqkv, Wo, W1, W2, src, wqkv_b);

  for (int l = 0; l < LNUM; ++l) {
    gemm128<0><<<dim3(3072 / 128, MROWS / 128, 1), 256, 0, stream>>>(
        xb, wqkv_b + (size_t)l * 3072 * 1024, bqkv + l * 3072, qkvb, 3072, 1024, 1024);
    attn_band<<<(BATCH * NHEAD * SEQ) / 4, 256, 0, stream>>>(qkvb, aob);
    gemm128<2><<<dim3(1024 / 128, MROWS / 128, 2), 256, 0, stream>>>(
        aob, wo_b + (size_t)l * 1024 * 1024, bo + l * 1024, part, 1024, 1024, 512);
    add_ln<2><<<MROWS, 256, 0, stream>>>(l == 0 ? src : nullptr, xb, part,
                                         ln1w + l * DMODEL, ln1b + l * DMODEL, nullptr);
    gemm128<1><<<dim3(FDIM / 128, MROWS / 128, 1), 256, 0, stream>>>(
        xb, w1_b + (size_t)l * 4096 * 1024, b1 + l * FDIM, hb, FDIM, 1024, 1024);
    gemm128<2><<<dim3(1024 / 128, MROWS / 128, 4), 256, 0, stream>>>(
        hb, w2_b + (size_t)l * 1024 * 4096, b2 + l * 1024, part, 1024, 4096, 1024);
    add_ln<4><<<MROWS, 256, 0, stream>>>(nullptr, xb, part,
                                         ln2w + l * DMODEL, ln2b + l * DMODEL,
                                         (l == LNUM - 1) ? out : nullptr);
  }
}

// Round 24
// 809.976 us; speedup vs baseline: 1.0330x; 1.0330x over previous
//
#include <hip/hip_runtime.h>

#define LNUM 4
#define DMODEL 1024
#define NHEAD 16
#define FDIM 4096
#define BATCH 4
#define SEQ 1024
#define HDIM 64
#define KBAND 8
#define MROWS (BATCH * SEQ)

typedef __attribute__((ext_vector_type(8))) __bf16 bf16x8;
typedef __attribute__((ext_vector_type(4))) float f32x4;
typedef __attribute__((ext_vector_type(8))) unsigned short u16x8;

__device__ __forceinline__ unsigned short f2bf(float f) {
  unsigned int u = __builtin_bit_cast(unsigned int, f);
  u = u + 0x7fffu + ((u >> 16) & 1u);
  return (unsigned short)(u >> 16);
}
__device__ __forceinline__ float bf2f(unsigned short h) {
  unsigned int u = ((unsigned int)h) << 16;
  return __builtin_bit_cast(float, u);
}

#define GLOAD16(gp, lp)                                                        \
  __builtin_amdgcn_global_load_lds(                                            \
      (const __attribute__((address_space(1))) void*)(gp),                     \
      (__attribute__((address_space(3))) void*)(lp), 16, 0, 0)

// ---------------- fused fp32 -> bf16 conversion (all 5 regions, 1 launch) ---
// R24 = R23 with stores reverted to REGULAR (cached): R23's NT stores made
// the 84MB bf16 weight region bypass L3, turning the GEMMs' weight reads
// into HBM fetches (+47us across 16 dispatches, total 822->837). NT LOADS
// kept: fp32 sources are read-once (218MB) and shouldn't evict useful
// lines. cvt_all itself: 87 -> 55us (4.0TB/s) from direct-indexed
// max-concurrency + 8 elems/thread (R23 confirmed parallelism-bound).
#define CVT_O1 12582912L
#define CVT_O2 16777216L
#define CVT_O3 33554432L
#define CVT_O4 50331648L
#define CVT_TOT 54525952L
__global__ __launch_bounds__(256) void cvt_all(const float* __restrict__ s0,
                                               const float* __restrict__ s1,
                                               const float* __restrict__ s2,
                                               const float* __restrict__ s3,
                                               const float* __restrict__ s4,
                                               unsigned short* __restrict__ dst) {
  const long i = ((long)blockIdx.x * 256 + threadIdx.x) * 8;
  if (i >= CVT_TOT) return;
  const float* sp;
  if (i < CVT_O1)      sp = s0 + i;
  else if (i < CVT_O2) sp = s1 + (i - CVT_O1);
  else if (i < CVT_O3) sp = s2 + (i - CVT_O2);
  else if (i < CVT_O4) sp = s3 + (i - CVT_O3);
  else                 sp = s4 + (i - CVT_O4);
  f32x4 v0 = __builtin_nontemporal_load(reinterpret_cast<const f32x4*>(sp));
  f32x4 v1 = __builtin_nontemporal_load(reinterpret_cast<const f32x4*>(sp + 4));
  u16x8 o;
  o[0] = f2bf(v0[0]); o[1] = f2bf(v0[1]); o[2] = f2bf(v0[2]); o[3] = f2bf(v0[3]);
  o[4] = f2bf(v1[0]); o[5] = f2bf(v1[1]); o[6] = f2bf(v1[2]); o[7] = f2bf(v1[3]);
  *reinterpret_cast<u16x8*>(dst + i) = o;  // REGULAR store: stays in L2/L3
}

// ---------------- 128x128 bf16 GEMM, BK=64 single-buffer (R16 exact) --------
// CHAMPION config (R16/R19/R20/R21: GEMMs ~50us, FETCH 25MB, MfmaUtil 27%,
// conflicts 131K). Measured-closed axes: schedule (6 variants all regress vs
// drain-0+TLP at these shapes); tile (256^2, 256x128 lose); BK (32 worse).
// Per iter: stage 8 gload_lds (32KB) -> __syncthreads -> 16 ds_read +
// 32 MFMA -> __syncthreads; latency hidden by 3-4 resident blocks/CU (m114).
// Swizzle for 128B rows: stored (row,g) holds source granule g^((row>>1)&7);
// read quad = kg^((fr>>1)&7) -> conflict-free. 8x8 super-tile under XCD
// chunking: per-XCD working set = L2 (FETCH 53->25MB). Epilogue: wave-
// private LDS transpose, full 64B-line stores.
// blockIdx.z = K-split; EPI: 0 bf16+bias, 1 bf16+bias+gelu, 2 bf16 partial.
template <int EPI>
__global__ __launch_bounds__(256, 4) void gemm128(const unsigned short* __restrict__ A,
                                                  const unsigned short* __restrict__ W,
                                                  const float* __restrict__ bias,
                                                  unsigned short* __restrict__ Cout,
                                                  int Ndim, int Kdim, int Ks) {
  __shared__ unsigned short SH[16384];  // As=SH[0:8192], Bs=SH[8192:16384]
  unsigned short* As = SH;
  unsigned short* Bs = SH + 8192;
  const int tid = threadIdx.x;
  const int wave = tid >> 6;
  const int lane = tid & 63;

  const int gx = gridDim.x, gy = gridDim.y;
  const int nwg = gx * gy;
  const int lin = blockIdx.x + blockIdx.y * gx;
  const int q8 = nwg >> 3, r8 = nwg & 7;
  const int xcd = lin & 7, cidx = lin >> 3;
  const int cbase = (xcd < r8) ? xcd * (q8 + 1) : r8 * (q8 + 1) + (xcd - r8) * q8;
  const int swz = cbase + cidx;
  const int sup = swz >> 6, inn = swz & 63;       // super-tile = 64 wg
  const int sbm = sup % (gy >> 3);
  const int sbn = sup / (gy >> 3);
  const int bm0 = (sbm * 8 + (inn & 7)) * 128;
  const int bn0 = (sbn * 8 + (inn >> 3)) * 128;
  const int kz0 = blockIdx.z * Ks;

  const int r0 = tid >> 3;                               // 0..31
  const int c0 = (((tid & 7) ^ ((tid >> 4) & 7)) << 3);  // swizzled col elem
  const unsigned short* gA = A + (size_t)(bm0 + r0) * Kdim + kz0 + c0;
  const unsigned short* gB = W + (size_t)(bn0 + r0) * Kdim + kz0 + c0;
  const size_t rs32 = (size_t)32 * Kdim;

  f32x4 acc[4][4] = {};

  const int wr = (wave >> 1) * 64;
  const int wc = (wave & 1) * 64;
  const int fr = lane & 15;
  const int rkey = (fr >> 1) & 7;

  const int nt = Ks >> 6;
  for (int t = 0; t < nt; ++t) {
#pragma unroll
    for (int i = 0; i < 4; ++i) {
      GLOAD16(gA + i * rs32, &As[i * 2048 + wave * 512]);
      GLOAD16(gB + i * rs32, &Bs[i * 2048 + wave * 512]);
    }
    gA += 64;
    gB += 64;
    __syncthreads();
#pragma unroll
    for (int ks = 0; ks < 2; ++ks) {
      const int kg0 = (lane >> 4) + 4 * ks;
      const int kofs = ((kg0 ^ rkey) << 3);
      bf16x8 af[4], bfr[4];
#pragma unroll
      for (int i = 0; i < 4; ++i)
        af[i] = *reinterpret_cast<const bf16x8*>(&As[(wr + i * 16 + fr) * 64 + kofs]);
#pragma unroll
      for (int j = 0; j < 4; ++j)
        bfr[j] = *reinterpret_cast<const bf16x8*>(&Bs[(wc + j * 16 + fr) * 64 + kofs]);
#pragma unroll
      for (int i = 0; i < 4; ++i)
#pragma unroll
        for (int j = 0; j < 4; ++j)
          acc[i][j] = __builtin_amdgcn_mfma_f32_16x16x32_bf16(af[i], bfr[j], acc[i][j], 0, 0, 0);
    }
    __syncthreads();
  }

  const int rr = (lane >> 4) * 4;
  const int cc = lane & 15;
  const bool addb = (EPI != 2) || (blockIdx.z == 0);
  unsigned short* outZ =
      Cout + (EPI == 2 ? (size_t)blockIdx.z * ((size_t)gy * 128) * Ndim : 0);
  float bv[4];
#pragma unroll
  for (int j = 0; j < 4; ++j)
    bv[j] = addb ? bias[bn0 + wc + j * 16 + cc] : 0.0f;

  unsigned short* lt = SH + wave * 1280;
#pragma unroll
  for (int rh = 0; rh < 2; ++rh) {
#pragma unroll
    for (int cp = 0; cp < 2; ++cp) {
#pragma unroll
      for (int ii = 0; ii < 2; ++ii)
#pragma unroll
        for (int jj = 0; jj < 2; ++jj)
#pragma unroll
          for (int r = 0; r < 4; ++r) {
            float v = acc[rh * 2 + ii][cp * 2 + jj][r] + bv[cp * 2 + jj];
            if (EPI == 1) v = 0.5f * v * (1.0f + erff(v * 0.70710678118654752f));
            lt[(ii * 16 + rr + r) * 40 + jj * 16 + cc] = f2bf(v);
          }
      asm volatile("s_waitcnt lgkmcnt(0)" ::: "memory");
      const int rl = lane >> 1;
      const int chalf = (lane & 1) * 16;
      u16x8 o0 = *reinterpret_cast<const u16x8*>(&lt[rl * 40 + chalf]);
      u16x8 o1 = *reinterpret_cast<const u16x8*>(&lt[rl * 40 + chalf + 8]);
      const int m = bm0 + wr + rh * 32 + rl;
      const int n0 = bn0 + wc + cp * 32 + chalf;
      unsigned short* dst = outZ + (size_t)m * Ndim + n0;
      *reinterpret_cast<u16x8*>(dst) = o0;
      *reinterpret_cast<u16x8*>(dst + 8) = o1;
      asm volatile("s_waitcnt lgkmcnt(0)" ::: "memory");
    }
  }
}

// ---------------- banded attention: one wave per (b,h,q), lane = d ----------
__global__ __launch_bounds__(256) void attn_band(const unsigned short* __restrict__ qkv,
                                                 unsigned short* __restrict__ outp) {
  const int gw = blockIdx.x * 4 + (threadIdx.x >> 6);
  const int lane = threadIdx.x & 63;
  const int q = gw & (SEQ - 1);
  const int bh = gw >> 10;
  const int h = bh & (NHEAD - 1);
  const int b = bh >> 4;
  const size_t row0 = (size_t)(b * SEQ + q);
  const size_t stride = 3 * DMODEL;
  const float qv = bf2f(qkv[row0 * stride + h * HDIM + lane]);

  float sc[KBAND];
  float mx = -1e30f;
#pragma unroll
  for (int jj = 0; jj < KBAND; ++jj) {
    const int j = q + jj;
    const int jc = (j < SEQ) ? j : (SEQ - 1);
    float kv = bf2f(qkv[(size_t)(b * SEQ + jc) * stride + DMODEL + h * HDIM + lane]);
    float p = qv * kv;
#pragma unroll
    for (int m = 32; m; m >>= 1) p += __shfl_xor(p, m);
    p *= 0.125f;
    p = (j < SEQ) ? p : -1e30f;
    sc[jj] = p;
    mx = fmaxf(mx, p);
  }
  float denom = 0.f;
  float ov = 0.f;
#pragma unroll
  for (int jj = 0; jj < KBAND; ++jj) {
    const int j = q + jj;
    const int jc = (j < SEQ) ? j : (SEQ - 1);
    float p = __expf(sc[jj] - mx);
    p = (j < SEQ) ? p : 0.f;
    denom += p;
    ov += p * bf2f(qkv[(size_t)(b * SEQ + jc) * stride + 2 * DMODEL + h * HDIM + lane]);
  }
  ov /= denom;
  outp[row0 * DMODEL + h * HDIM + lane] = f2bf(ov);
}

// ---------------- residual(bf16, in-place) + split-K reduce + LayerNorm -----
template <int NZ>
__global__ __launch_bounds__(256) void add_ln(const float* __restrict__ srcf,
                                              unsigned short* __restrict__ xb,
                                              const unsigned short* __restrict__ part,
                                              const float* __restrict__ gw,
                                              const float* __restrict__ gb,
                                              float* __restrict__ outf) {
  const int row = blockIdx.x;
  const int tid = threadIdx.x;
  const size_t slab = (size_t)MROWS * DMODEL;
  unsigned short* xp = xb + (size_t)row * DMODEL;
  const unsigned short* pp = part + (size_t)row * DMODEL;
  float v[4];
  float s = 0.f, s2 = 0.f;
#pragma unroll
  for (int i = 0; i < 4; ++i) {
    const int idx = tid + i * 256;
    float a = srcf ? srcf[(size_t)row * DMODEL + idx] : bf2f(xp[idx]);
#pragma unroll
    for (int z = 0; z < NZ; ++z) a += bf2f(pp[z * slab + idx]);
    v[i] = a;
    s += a;
    s2 += a * a;
  }
#pragma unroll
  for (int m = 32; m; m >>= 1) {
    s += __shfl_xor(s, m);
    s2 += __shfl_xor(s2, m);
  }
  __shared__ float wsm[8];
  const int wave = tid >> 6, lane = tid & 63;
  if (lane == 0) {
    wsm[wave] = s;
    wsm[4 + wave] = s2;
  }
  __syncthreads();
  s = wsm[0] + wsm[1] + wsm[2] + wsm[3];
  s2 = wsm[4] + wsm[5] + wsm[6] + wsm[7];
  const float mean = s * (1.f / DMODEL);
  const float var = s2 * (1.f / DMODEL) - mean * mean;
  const float rstd = rsqrtf(var + 1e-5f);
#pragma unroll
  for (int i = 0; i < 4; ++i) {
    const int idx = tid + i * 256;
    const float y = (v[i] - mean) * rstd * gw[idx] + gb[idx];
    xp[idx] = f2bf(y);
    if (outf) outf[(size_t)row * DMODEL + idx] = y;
  }
}

extern "C" void kernel_launch(void* const* d_in, const int* in_sizes, int n_in,
                              void* d_out, int out_size, void* d_ws, size_t ws_size,
                              hipStream_t stream) {
  const float* src  = (const float*)d_in[0];
  const float* Wqkv = (const float*)d_in[1];
  const float* bqkv = (const float*)d_in[2];
  const float* Wo   = (const float*)d_in[3];
  const float* bo   = (const float*)d_in[4];
  const float* W1   = (const float*)d_in[5];
  const float* b1   = (const float*)d_in[6];
  const float* W2   = (const float*)d_in[7];
  const float* b2   = (const float*)d_in[8];
  const float* ln1w = (const float*)d_in[9];
  const float* ln1b = (const float*)d_in[10];
  const float* ln2w = (const float*)d_in[11];
  const float* ln2b = (const float*)d_in[12];
  float* out = (float*)d_out;

  // workspace carve-up (~168 MB of 209.7 MB). wqkv_b..xb CONTIGUOUS.
  char* p = (char*)d_ws;
  unsigned short* wqkv_b = (unsigned short*)p; p += (size_t)LNUM * 3072 * 1024 * 2;
  unsigned short* wo_b   = (unsigned short*)p; p += (size_t)LNUM * 1024 * 1024 * 2;
  unsigned short* w1_b   = (unsigned short*)p; p += (size_t)LNUM * 4096 * 1024 * 2;
  unsigned short* w2_b   = (unsigned short*)p; p += (size_t)LNUM * 1024 * 4096 * 2;
  unsigned short* xb     = (unsigned short*)p; p += (size_t)MROWS * DMODEL * 2;
  char* R = p;
  unsigned short* qkvb = (unsigned short*)R;
  unsigned short* aob  = (unsigned short*)(R + (size_t)MROWS * 3 * DMODEL * 2);
  unsigned short* hb   = (unsigned short*)R;
  unsigned short* part = (unsigned short*)(R + (size_t)MROWS * 4096 * 2);
  p = R + (size_t)MROWS * 4096 * 2 + (size_t)4 * MROWS * DMODEL * 2;
  if (ws_size < (size_t)(p - (char*)d_ws)) return;

  // single fused conversion sweep: Wqkv|Wo|W1|W2|src -> contiguous bf16
  cvt_all<<<(CVT_TOT / 8 + 255) / 256, 256, 0, stream>>>(Wqkv, Wo, W1, W2, src, wqkv_b);

  for (int l = 0; l < LNUM; ++l) {
    gemm128<0><<<dim3(3072 / 128, MROWS / 128, 1), 256, 0, stream>>>(
        xb, wqkv_b + (size_t)l * 3072 * 1024, bqkv + l * 3072, qkvb, 3072, 1024, 1024);
    attn_band<<<(BATCH * NHEAD * SEQ) / 4, 256, 0, stream>>>(qkvb, aob);
    gemm128<2><<<dim3(1024 / 128, MROWS / 128, 2), 256, 0, stream>>>(
        aob, wo_b + (size_t)l * 1024 * 1024, bo + l * 1024, part, 1024, 1024, 512);
    add_ln<2><<<MROWS, 256, 0, stream>>>(l == 0 ? src : nullptr, xb, part,
                                         ln1w + l * DMODEL, ln1b + l * DMODEL, nullptr);
    gemm128<1><<<dim3(FDIM / 128, MROWS / 128, 1), 256, 0, stream>>>(
        xb, w1_b + (size_t)l * 4096 * 1024, b1 + l * FDIM, hb, FDIM, 1024, 1024);
    gemm128<2><<<dim3(1024 / 128, MROWS / 128, 4), 256, 0, stream>>>(
        hb, w2_b + (size_t)l * 1024 * 4096, b2 + l * 1024, part, 1024, 4096, 1024);
    add_ln<4><<<MROWS, 256, 0, stream>>>(nullptr, xb, part,
                                         ln2w + l * DMODEL, ln2b + l * DMODEL,
                                         (l == LNUM - 1) ? out : nullptr);
  }
}